// Round 6
// baseline (168.459 us; speedup 1.0000x reference)
//
#include <hip/hip_runtime.h>
#include <math.h>

#define B_  4096
#define C_  64
#define LQ_ 32
#define D_  128
#define H_  192

typedef __attribute__((ext_vector_type(8))) short bf16x8;
typedef __attribute__((ext_vector_type(4))) float f32x4;

#define KEEP(x) asm volatile("" : "+v"(x))

__device__ inline unsigned cvt_pk_bf16(float lo, float hi) {
    unsigned r;
    asm("v_cvt_pk_bf16_f32 %0, %1, %2" : "=v"(r) : "v"(lo), "v"(hi));
    return r;
}
__device__ inline short f2b(float x) { return (short)(cvt_pk_bf16(x, x) & 0xffff); }
__device__ inline float sigm(float x) { return 1.f / (1.f + __expf(-x)); }

// Raw barrier: waits LDS ops only; leaves global loads in flight (T4).
__device__ inline void wg_barrier() {
    asm volatile("s_waitcnt lgkmcnt(0)" ::: "memory");
    __builtin_amdgcn_s_barrier();
    asm volatile("" ::: "memory");
}

// ---------------------------------------------------------------------------
// Prep: transpose + convert weights to bf16.
// ---------------------------------------------------------------------------
__global__ __launch_bounds__(256) void prep_kernel(
    const float* __restrict__ W1, const float* __restrict__ W2,
    const float* __restrict__ Wx, const float* __restrict__ Wh,
    short* __restrict__ W1T, short* __restrict__ W2T, short* __restrict__ WTl)
{
    int idx = blockIdx.x * 256 + threadIdx.x;   // 0 .. 131071
    if (idx < 192 * 256) {
        int j = idx >> 8, k = idx & 255;
        W1T[idx] = f2b(W1[k * H_ + j]);
    }
    if (idx < 128 * 192) {
        int j = idx / 192, k = idx - j * 192;
        W2T[idx] = f2b(W2[k * D_ + j]);
    }
    if (idx < 512 * 256) {
        int p = idx >> 8, k = idx & 255;
        int w = p >> 6, g = (p >> 4) & 3, jj = p & 15;
        int jo = g * 128 + w * 16 + jj;
        float v = (k < 128) ? Wx[k * 512 + jo] : Wh[(k - 128) * 512 + jo];
        WTl[idx] = f2b(v);
    }
}

// ---------------------------------------------------------------------------
// Table encoder v6: persistent blocks (256 x 512thr, 16 b's each),
// DEPTH-2 register prefetch (pf0/pf1 ping-pong -> HBM never idles),
// swapped-operand MFMA (D[j][r]: j-consecutive in regs -> b64 h-stores),
// raw barriers (no vmcnt drain in the loop).
// Wave (wr=w>>2, ww=w&3): rows [wr*16..+16), GEMM1 j [ww*48..+48),
// GEMM2 j2 [ww*32..+32).
// ---------------------------------------------------------------------------
__global__ __launch_bounds__(512) __attribute__((amdgpu_waves_per_eu(1, 2)))
void table_kernel(
    const float* __restrict__ header, const float* __restrict__ tword,
    const float* __restrict__ masks, const int* __restrict__ num_cols,
    const short* __restrict__ W1T, const float* __restrict__ b1,
    const short* __restrict__ W2T, const float* __restrict__ b2,
    float* __restrict__ te_out)
{
    const int bb0 = blockIdx.x * 16;
    const int tid = threadIdx.x;
    const int w   = tid >> 6;
    const int l   = tid & 63;
    const int lg  = l >> 4;
    const int ln  = l & 15;
    const int ww  = w & 3;
    const int wr  = w >> 2;

    __shared__ __align__(16) short flat_s[2][32 * 256];  // 2 x 16 KB, swizzled
    __shared__ __align__(16) short h_s[32 * 192];        // 12 KB, swizzled
    __shared__ float msk_s[16][64];                      // 4 KB
    __shared__ float ncol_s[16];
    __shared__ float redv2[2][128];                      // 1 KB
    __shared__ float redq[2];

    // ---- resident weights (pinned). Swapped-operand layout:
    //      bw1[ct] rows j = ww*48+ct*16+ln; bias now per (lg,reg).
    bf16x8 bw1[3][8];
    float bias1[3][4];
    #pragma unroll
    for (int ct = 0; ct < 3; ++ct) {
        int j = ww * 48 + ct * 16 + ln;
        #pragma unroll
        for (int ks = 0; ks < 8; ++ks)
            bw1[ct][ks] = *(const bf16x8*)&W1T[j * 256 + ks * 32 + lg * 8];
        #pragma unroll
        for (int reg = 0; reg < 4; ++reg)
            bias1[ct][reg] = b1[ww * 48 + ct * 16 + lg * 4 + reg];
    }
    bf16x8 bw2[2][6];
    float bias2[2][4];
    #pragma unroll
    for (int ct = 0; ct < 2; ++ct) {
        int j = ww * 32 + ct * 16 + ln;
        #pragma unroll
        for (int ks = 0; ks < 6; ++ks)
            bw2[ct][ks] = *(const bf16x8*)&W2T[j * 192 + ks * 32 + lg * 8];
        #pragma unroll
        for (int reg = 0; reg < 4; ++reg)
            bias2[ct][reg] = b2[ww * 32 + ct * 16 + lg * 4 + reg];
    }
    #pragma unroll
    for (int ct = 0; ct < 3; ++ct) {
        #pragma unroll
        for (int ks = 0; ks < 8; ++ks) KEEP(bw1[ct][ks]);
        #pragma unroll
        for (int reg = 0; reg < 4; ++reg) KEEP(bias1[ct][reg]);
    }
    #pragma unroll
    for (int ct = 0; ct < 2; ++ct) {
        #pragma unroll
        for (int ks = 0; ks < 6; ++ks) KEEP(bw2[ct][ks]);
        #pragma unroll
        for (int reg = 0; reg < 4; ++reg) KEEP(bias2[ct][reg]);
    }

    // ---- preload masks + num_cols for the 16 b's
    *(float2*)&((float*)msk_s)[tid * 2] =
        *(const float2*)&masks[(size_t)bb0 * C_ + tid * 2];   // 512thr x 2 = 1024
    if (tid < 16) ncol_s[tid] = (float)num_cols[bb0 + tid];
    __syncthreads();

    // ---- depth-2 prefetch: two 32-row chunks in flight at all times
    float4 pf0[4], pf1[4];
    auto issue = [&](int cc, float4 (&dst)[4]) {
        int b    = bb0 + (cc >> 1);
        int row0 = (cc & 1) * 32;
        #pragma unroll
        for (int i = 0; i < 4; ++i) {
            int idx = i * 512 + tid;
            int r   = idx >> 6;
            int c   = idx & 63;
            const float* src = (c < 32)
                ? &header[((size_t)b * C_ + row0 + r) * D_ + c * 4]
                : &tword [((size_t)b * C_ + row0 + r) * D_ + (c - 32) * 4];
            dst[i] = *(const float4*)src;
        }
    };
    issue(0, pf0);
    issue(1, pf1);

    float csum[2][4] = {{0.f, 0.f, 0.f, 0.f}, {0.f, 0.f, 0.f, 0.f}};
    const int row = wr * 16 + ln;                 // this wave's tile row
    const int swz = (row & 7) << 4;

    auto body = [&](int cc, int half, float4 (&pfc)[4], char* fbuf) {
        const int bi = cc >> 1;

        // (a) write prefetched chunk -> flat_s (bf16, swizzled); waits only
        //     this slot's loads (issued 2 chunks ago -> latency covered)
        #pragma unroll
        for (int i = 0; i < 4; ++i) {
            int idx = i * 512 + tid;
            int r   = idx >> 6;
            int c   = idx & 63;
            uint2 p;
            p.x = cvt_pk_bf16(pfc[i].x, pfc[i].y);
            p.y = cvt_pk_bf16(pfc[i].z, pfc[i].w);
            *(uint2*)(fbuf + r * 512 + ((c * 8) ^ ((r & 7) << 4))) = p;
        }
        // (b) refill this slot 2 chunks ahead
        if (cc + 2 < 32) issue(cc + 2, pfc);
        wg_barrier();   // (c) flat ready

        // ---- GEMM1 swapped: D[j][r] = W1(j,k) x flat^T(k,r); lane holds
        //      4 consecutive j at its row -> one b64 store per ct
        {
            f32x4 acc[3];
            #pragma unroll
            for (int ct = 0; ct < 3; ++ct)
                acc[ct] = (f32x4){bias1[ct][0], bias1[ct][1], bias1[ct][2], bias1[ct][3]};
            #pragma unroll
            for (int ks = 0; ks < 8; ++ks) {
                bf16x8 a = *(const bf16x8*)(fbuf + row * 512 + ((ks * 64 + lg * 16) ^ swz));
                #pragma unroll
                for (int ct = 0; ct < 3; ++ct)
                    acc[ct] = __builtin_amdgcn_mfma_f32_16x16x32_bf16(bw1[ct][ks], a, acc[ct], 0, 0, 0);
            }
            #pragma unroll
            for (int ct = 0; ct < 3; ++ct) {
                int col0 = ww * 48 + ct * 16 + lg * 4;
                uint2 hp;
                hp.x = cvt_pk_bf16(fmaxf(acc[ct][0], 0.f), fmaxf(acc[ct][1], 0.f));
                hp.y = cvt_pk_bf16(fmaxf(acc[ct][2], 0.f), fmaxf(acc[ct][3], 0.f));
                *(uint2*)((char*)h_s + row * 384 + ((col0 * 2) ^ swz)) = hp;
            }
        }
        wg_barrier();   // (e) h ready

        // ---- GEMM2 swapped + fused mask*column-sum (mask uniform per lane)
        {
            f32x4 acc2[2];
            #pragma unroll
            for (int ct = 0; ct < 2; ++ct)
                acc2[ct] = (f32x4){bias2[ct][0], bias2[ct][1], bias2[ct][2], bias2[ct][3]};
            #pragma unroll
            for (int ks = 0; ks < 6; ++ks) {
                bf16x8 a = *(const bf16x8*)((char*)h_s + row * 384 + ((ks * 64 + lg * 16) ^ swz));
                #pragma unroll
                for (int ct = 0; ct < 2; ++ct)
                    acc2[ct] = __builtin_amdgcn_mfma_f32_16x16x32_bf16(bw2[ct][ks], a, acc2[ct], 0, 0, 0);
            }
            float m = msk_s[bi][half * 32 + row];
            #pragma unroll
            for (int ct = 0; ct < 2; ++ct)
                #pragma unroll
                for (int reg = 0; reg < 4; ++reg)
                    csum[ct][reg] = fmaf(fmaxf(acc2[ct][reg], 0.f), m, csum[ct][reg]);
        }

        // ---- end of b: reduce over rows (ln-butterfly + cross-wr), l2norm
        if (half == 1) {
            #pragma unroll
            for (int s = 1; s < 16; s <<= 1)
                #pragma unroll
                for (int ct = 0; ct < 2; ++ct)
                    #pragma unroll
                    for (int reg = 0; reg < 4; ++reg)
                        csum[ct][reg] += __shfl_xor(csum[ct][reg], s, 64);
            if (ln == 0) {
                #pragma unroll
                for (int ct = 0; ct < 2; ++ct)
                    #pragma unroll
                    for (int reg = 0; reg < 4; ++reg)
                        redv2[wr][ww * 32 + ct * 16 + lg * 4 + reg] = csum[ct][reg];
            }
            wg_barrier();
            float v = 0.f;
            if (tid < 128) {
                v = (redv2[0][tid] + redv2[1][tid]) / ncol_s[bi];
                float s2 = v * v;
                #pragma unroll
                for (int sh = 1; sh < 64; sh <<= 1) s2 += __shfl_xor(s2, sh, 64);
                if (l == 0) redq[w] = s2;
            }
            wg_barrier();
            if (tid < 128) {
                float inv = rsqrtf(fmaxf(redq[0] + redq[1], 1e-12f));
                te_out[(size_t)(bb0 + bi) * D_ + tid] = v * inv;
            }
            #pragma unroll
            for (int ct = 0; ct < 2; ++ct)
                #pragma unroll
                for (int reg = 0; reg < 4; ++reg)
                    csum[ct][reg] = 0.f;
        }
    };

    for (int bi = 0; bi < 16; ++bi) {
        body(bi * 2,     0, pf0, (char*)flat_s[0]);
        body(bi * 2 + 1, 1, pf1, (char*)flat_s[1]);
    }
}

// ---------------------------------------------------------------------------
// LSTM v6: 256 blocks x 512 threads, 16 rows/block, depth-2 x prefetch,
// raw barriers, weights pinned resident.
// ---------------------------------------------------------------------------
__global__ __launch_bounds__(512) __attribute__((amdgpu_waves_per_eu(1, 2)))
void lstm_kernel(
    const float* __restrict__ q, const int* __restrict__ lengths,
    const short* __restrict__ WTl, const float* __restrict__ bl,
    float* __restrict__ qe_out)
{
    const int tid = threadIdx.x;
    const int b0  = blockIdx.x * 16;
    const int w   = tid >> 6;
    const int l   = tid & 63;
    const int lg  = l >> 4;
    const int ln  = l & 15;       // batch row within block
    const int d0  = w * 16 + lg * 4;

    __shared__ __align__(16) short xh[2][16 * 256];  // 2 x 8 KB, swizzled
    __shared__ float red8[8][16];

    bf16x8 wf[4][8];
    #pragma unroll
    for (int g = 0; g < 4; ++g)
        #pragma unroll
        for (int ks = 0; ks < 8; ++ks)
            wf[g][ks] = *(const bf16x8*)&WTl[(w * 64 + g * 16 + ln) * 256 + ks * 32 + lg * 8];
    float bias[4][4];
    #pragma unroll
    for (int g = 0; g < 4; ++g)
        #pragma unroll
        for (int reg = 0; reg < 4; ++reg)
            bias[g][reg] = bl[g * 128 + d0 + reg];
    #pragma unroll
    for (int g = 0; g < 4; ++g) {
        #pragma unroll
        for (int ks = 0; ks < 8; ++ks) KEEP(wf[g][ks]);
        #pragma unroll
        for (int reg = 0; reg < 4; ++reg) KEEP(bias[g][reg]);
    }

    float creg[4] = {0.f, 0.f, 0.f, 0.f};
    float hreg[4] = {0.f, 0.f, 0.f, 0.f};
    const int len = lengths[b0 + ln];
    const int sr = tid >> 5, sc = tid & 31;
    const float* qbase = &q[((size_t)(b0 + sr) * LQ_) * D_ + sc * 4];

    float4 qv0 = *(const float4*)&qbase[0 * D_];
    float4 qv1 = *(const float4*)&qbase[1 * D_];

    auto step = [&](int t, float4& qvc, char* buf) {
        // stage x_t from prefetched regs
        uint2 px; px.x = cvt_pk_bf16(qvc.x, qvc.y); px.y = cvt_pk_bf16(qvc.z, qvc.w);
        *(uint2*)(buf + sr * 512 + ((sc * 8) ^ ((sr & 7) << 4))) = px;
        // write h(t-1)
        uint2 ph; ph.x = cvt_pk_bf16(hreg[0], hreg[1]); ph.y = cvt_pk_bf16(hreg[2], hreg[3]);
        *(uint2*)(buf + ln * 512 + ((256 + d0 * 2) ^ ((ln & 7) << 4))) = ph;
        // refill this slot 2 steps ahead
        if (t + 2 < LQ_) qvc = *(const float4*)&qbase[(size_t)(t + 2) * D_];
        wg_barrier();

        f32x4 acc[4];
        #pragma unroll
        for (int g = 0; g < 4; ++g)
            acc[g] = (f32x4){bias[g][0], bias[g][1], bias[g][2], bias[g][3]};
        #pragma unroll
        for (int ks = 0; ks < 8; ++ks) {
            bf16x8 xf = *(const bf16x8*)(buf + ln * 512 + ((ks * 64 + lg * 16) ^ ((ln & 7) << 4)));
            #pragma unroll
            for (int g = 0; g < 4; ++g)
                acc[g] = __builtin_amdgcn_mfma_f32_16x16x32_bf16(wf[g][ks], xf, acc[g], 0, 0, 0);
        }

        bool live = (t < len);
        #pragma unroll
        for (int reg = 0; reg < 4; ++reg) {
            float iv = sigm(acc[0][reg]);
            float fv = sigm(acc[1][reg]);
            float gv = fmaxf(acc[2][reg], 0.f);
            float ov = sigm(acc[3][reg]);
            float cn = fmaf(fv, creg[reg], iv * gv);
            float hn = ov * fmaxf(cn, 0.f);
            if (live) { creg[reg] = cn; hreg[reg] = hn; }
        }
    };

    for (int tt = 0; tt < LQ_; tt += 2) {
        step(tt,     qv0, (char*)xh[0]);
        step(tt + 1, qv1, (char*)xh[1]);
    }

    // l2norm per batch row
    float sq = 0.f;
    #pragma unroll
    for (int reg = 0; reg < 4; ++reg) sq = fmaf(hreg[reg], hreg[reg], sq);
    sq += __shfl_xor(sq, 16, 64);
    sq += __shfl_xor(sq, 32, 64);
    if (l < 16) red8[w][ln] = sq;
    wg_barrier();
    float tot = 0.f;
    #pragma unroll
    for (int ww = 0; ww < 8; ++ww) tot += red8[ww][ln];
    float inv = rsqrtf(fmaxf(tot, 1e-12f));
    float4 o;
    o.x = hreg[0] * inv; o.y = hreg[1] * inv; o.z = hreg[2] * inv; o.w = hreg[3] * inv;
    *(float4*)&qe_out[(size_t)(b0 + ln) * D_ + d0] = o;
}

// ---------------------------------------------------------------------------
// Loss: 64 blocks x 64 threads, 1 sample per thread.
// ---------------------------------------------------------------------------
__global__ __launch_bounds__(64) void loss_kernel(
    const float* __restrict__ te, const float* __restrict__ qe,
    const float* __restrict__ labels, float* __restrict__ partial)
{
    const int tid = threadIdx.x;
    const int b   = blockIdx.x * 64 + tid;
    float dsum = 0.f;
    #pragma unroll 8
    for (int k4 = 0; k4 < 32; ++k4) {
        float4 a = *(const float4*)&qe[(size_t)b * D_ + k4 * 4];
        float4 c = *(const float4*)&te[(size_t)b * D_ + k4 * 4];
        float dx = a.x - c.x, dy = a.y - c.y, dz = a.z - c.z, dw = a.w - c.w;
        dsum += dx * dx + dy * dy + dz * dz + dw * dw;
    }
    float lab = labels[b];
    float ds  = sqrtf(dsum);
    float ml  = fmaxf(0.f, 1.f - ds);
    float loss = lab * dsum + (1.f - lab) * ml * ml;
    #pragma unroll
    for (int s = 32; s > 0; s >>= 1) loss += __shfl_xor(loss, s, 64);
    if (tid == 0) partial[blockIdx.x] = loss;
}

__global__ void final_kernel(const float* __restrict__ partial, float* __restrict__ out)
{
    const int tid = threadIdx.x;   // 64 threads
    float v = partial[tid];
    #pragma unroll
    for (int s = 32; s > 0; s >>= 1) v += __shfl_xor(v, s, 64);
    if (tid == 0) out[0] = 0.5f * v / (float)B_;
}

// ---------------------------------------------------------------------------
extern "C" void kernel_launch(void* const* d_in, const int* in_sizes, int n_in,
                              void* d_out, int out_size, void* d_ws, size_t ws_size,
                              hipStream_t stream)
{
    const float* q      = (const float*)d_in[0];
    const int*   qlen   = (const int*)d_in[1];
    const float* header = (const float*)d_in[2];
    const float* tword  = (const float*)d_in[3];
    const int*   ncols  = (const int*)d_in[4];
    const float* masks  = (const float*)d_in[5];
    const float* labels = (const float*)d_in[6];
    const float* W1     = (const float*)d_in[7];
    const float* b1     = (const float*)d_in[8];
    const float* W2     = (const float*)d_in[9];
    const float* b2     = (const float*)d_in[10];
    const float* Wx     = (const float*)d_in[11];
    const float* Wh     = (const float*)d_in[12];
    const float* bl     = (const float*)d_in[13];
    float* out = (float*)d_out;

    float* te      = (float*)d_ws;
    float* qe      = te + (size_t)B_ * D_;
    float* partial = qe + (size_t)B_ * D_;
    short* W1T     = (short*)(partial + 64);          // 192*256
    short* W2T     = W1T + 192 * 256;                 // 128*192
    short* WTl     = W2T + 128 * 192;                 // 512*256

    prep_kernel<<<512, 256, 0, stream>>>(W1, W2, Wx, Wh, W1T, W2T, WTl);
    table_kernel<<<B_ / 16, 512, 0, stream>>>(header, tword, masks, ncols, W1T, b1, W2T, b2, te);
    lstm_kernel<<<B_ / 16, 512, 0, stream>>>(q, qlen, WTl, bl, qe);
    loss_kernel<<<B_ / 64, 64, 0, stream>>>(te, qe, labels, partial);
    final_kernel<<<1, 64, 0, stream>>>(partial, out);
}

// Round 7
// 150.835 us; speedup vs baseline: 1.1168x; 1.1168x over previous
//
#include <hip/hip_runtime.h>
#include <math.h>

#define B_  4096
#define C_  64
#define LQ_ 32
#define D_  128
#define H_  192

typedef __attribute__((ext_vector_type(8))) short bf16x8;
typedef __attribute__((ext_vector_type(4))) float f32x4;

#define KEEP(x) asm volatile("" : "+v"(x))

__device__ inline unsigned cvt_pk_bf16(float lo, float hi) {
    unsigned r;
    asm("v_cvt_pk_bf16_f32 %0, %1, %2" : "=v"(r) : "v"(lo), "v"(hi));
    return r;
}
__device__ inline short f2b(float x) { return (short)(cvt_pk_bf16(x, x) & 0xffff); }
__device__ inline float sigm(float x) { return 1.f / (1.f + __expf(-x)); }

// Raw barrier: waits LDS ops only; leaves global loads in flight (T4).
__device__ inline void wg_barrier() {
    asm volatile("s_waitcnt lgkmcnt(0)" ::: "memory");
    __builtin_amdgcn_s_barrier();
    asm volatile("" ::: "memory");
}

// ---------------------------------------------------------------------------
// Prep: transpose + convert weights to bf16.
// ---------------------------------------------------------------------------
__global__ __launch_bounds__(256) void prep_kernel(
    const float* __restrict__ W1, const float* __restrict__ W2,
    const float* __restrict__ Wx, const float* __restrict__ Wh,
    short* __restrict__ W1T, short* __restrict__ W2T, short* __restrict__ WTl)
{
    int idx = blockIdx.x * 256 + threadIdx.x;   // 0 .. 131071
    if (idx < 192 * 256) {
        int j = idx >> 8, k = idx & 255;
        W1T[idx] = f2b(W1[k * H_ + j]);
    }
    if (idx < 128 * 192) {
        int j = idx / 192, k = idx - j * 192;
        W2T[idx] = f2b(W2[k * D_ + j]);
    }
    if (idx < 512 * 256) {
        int p = idx >> 8, k = idx & 255;
        int w = p >> 6, g = (p >> 4) & 3, jj = p & 15;
        int jo = g * 128 + w * 16 + jj;
        float v = (k < 128) ? Wx[k * 512 + jo] : Wh[(k - 128) * 512 + jo];
        WTl[idx] = f2b(v);
    }
}

// ---------------------------------------------------------------------------
// Table encoder v7: 1024 blocks x 256 threads (4 waves), 4 b's per block ->
// 2+ independent workgroups per CU (cross-workgroup latency hiding; the v6
// persistent design had exactly 1 wg/CU so every stall idled the whole CU).
// 16-row chunks (4 per b), double-buffered flat_s, depth-2 pf ping-pong,
// swapped-operand MFMA, raw barriers.
// Wave w: GEMM1 j-cols [w*48..+48), GEMM2 j2-cols [w*32..+32), rows = all 16.
// ---------------------------------------------------------------------------
__global__ __launch_bounds__(256, 2)
void table_kernel(
    const float* __restrict__ header, const float* __restrict__ tword,
    const float* __restrict__ masks, const int* __restrict__ num_cols,
    const short* __restrict__ W1T, const float* __restrict__ b1,
    const short* __restrict__ W2T, const float* __restrict__ b2,
    float* __restrict__ te_out)
{
    const int bb0 = blockIdx.x * 4;
    const int tid = threadIdx.x;
    const int w   = tid >> 6;      // 0..3: column-group wave
    const int l   = tid & 63;
    const int lg  = l >> 4;
    const int ln  = l & 15;

    __shared__ __align__(16) short flat_s[2][16 * 256];  // 2 x 8 KB, swizzled
    __shared__ __align__(16) short h_s[16 * 192];        // 6 KB, swizzled
    __shared__ float msk_s[4][64];                       // 1 KB
    __shared__ float ncol_s[4];
    __shared__ float redv[128];
    __shared__ float redq[2];

    // ---- resident weights (swapped-operand layout), pinned (live in AGPRs)
    bf16x8 bw1[3][8];
    float bias1[3][4];
    #pragma unroll
    for (int ct = 0; ct < 3; ++ct) {
        int j = w * 48 + ct * 16 + ln;
        #pragma unroll
        for (int ks = 0; ks < 8; ++ks)
            bw1[ct][ks] = *(const bf16x8*)&W1T[j * 256 + ks * 32 + lg * 8];
        #pragma unroll
        for (int reg = 0; reg < 4; ++reg)
            bias1[ct][reg] = b1[w * 48 + ct * 16 + lg * 4 + reg];
    }
    bf16x8 bw2[2][6];
    float bias2[2][4];
    #pragma unroll
    for (int ct = 0; ct < 2; ++ct) {
        int j = w * 32 + ct * 16 + ln;
        #pragma unroll
        for (int ks = 0; ks < 6; ++ks)
            bw2[ct][ks] = *(const bf16x8*)&W2T[j * 192 + ks * 32 + lg * 8];
        #pragma unroll
        for (int reg = 0; reg < 4; ++reg)
            bias2[ct][reg] = b2[w * 32 + ct * 16 + lg * 4 + reg];
    }
    #pragma unroll
    for (int ct = 0; ct < 3; ++ct) {
        #pragma unroll
        for (int ks = 0; ks < 8; ++ks) KEEP(bw1[ct][ks]);
        #pragma unroll
        for (int reg = 0; reg < 4; ++reg) KEEP(bias1[ct][reg]);
    }
    #pragma unroll
    for (int ct = 0; ct < 2; ++ct) {
        #pragma unroll
        for (int ks = 0; ks < 6; ++ks) KEEP(bw2[ct][ks]);
        #pragma unroll
        for (int reg = 0; reg < 4; ++reg) KEEP(bias2[ct][reg]);
    }

    // ---- preload masks + num_cols for the 4 b's
    ((float*)msk_s)[tid] = masks[(size_t)bb0 * C_ + tid];
    if (tid < 4) ncol_s[tid] = (float)num_cols[bb0 + tid];
    __syncthreads();

    // ---- depth-2 prefetch: 4 float4/thread = one 16-row fp32 chunk
    float4 pf0[4], pf1[4];
    auto issue = [&](int cc, float4 (&dst)[4]) {
        int b    = bb0 + (cc >> 2);
        int row0 = (cc & 3) * 16;
        #pragma unroll
        for (int i = 0; i < 4; ++i) {
            int idx = i * 256 + tid;         // 0..1023 float4 slots
            int r   = idx >> 6;              // 0..15
            int c   = idx & 63;
            const float* src = (c < 32)
                ? &header[((size_t)b * C_ + row0 + r) * D_ + c * 4]
                : &tword [((size_t)b * C_ + row0 + r) * D_ + (c - 32) * 4];
            dst[i] = *(const float4*)src;
        }
    };
    issue(0, pf0);
    issue(1, pf1);

    float csum[2][4] = {{0.f, 0.f, 0.f, 0.f}, {0.f, 0.f, 0.f, 0.f}};
    const int row = ln;
    const int swz = (ln & 7) << 4;

    auto body = [&](int cc, float4 (&pfc)[4], char* fbuf) {
        const int bi = cc >> 2;

        // (a) write prefetched chunk -> flat_s (bf16, swizzled); the vmcnt
        //     wait here covers loads issued 2 chunks ago
        #pragma unroll
        for (int i = 0; i < 4; ++i) {
            int idx = i * 256 + tid;
            int r   = idx >> 6;
            int c   = idx & 63;
            uint2 p;
            p.x = cvt_pk_bf16(pfc[i].x, pfc[i].y);
            p.y = cvt_pk_bf16(pfc[i].z, pfc[i].w);
            *(uint2*)(fbuf + r * 512 + ((c * 8) ^ ((r & 7) << 4))) = p;
        }
        // (b) refill this slot 2 chunks ahead
        if (cc + 2 < 16) issue(cc + 2, pfc);
        wg_barrier();   // (c) flat ready

        // ---- GEMM1 swapped: D[j][r]; one b64 h-store per ct
        {
            f32x4 acc[3];
            #pragma unroll
            for (int ct = 0; ct < 3; ++ct)
                acc[ct] = (f32x4){bias1[ct][0], bias1[ct][1], bias1[ct][2], bias1[ct][3]};
            #pragma unroll
            for (int ks = 0; ks < 8; ++ks) {
                bf16x8 a = *(const bf16x8*)(fbuf + row * 512 + ((ks * 64 + lg * 16) ^ swz));
                #pragma unroll
                for (int ct = 0; ct < 3; ++ct)
                    acc[ct] = __builtin_amdgcn_mfma_f32_16x16x32_bf16(bw1[ct][ks], a, acc[ct], 0, 0, 0);
            }
            #pragma unroll
            for (int ct = 0; ct < 3; ++ct) {
                int col0 = w * 48 + ct * 16 + lg * 4;
                uint2 hp;
                hp.x = cvt_pk_bf16(fmaxf(acc[ct][0], 0.f), fmaxf(acc[ct][1], 0.f));
                hp.y = cvt_pk_bf16(fmaxf(acc[ct][2], 0.f), fmaxf(acc[ct][3], 0.f));
                *(uint2*)((char*)h_s + row * 384 + ((col0 * 2) ^ swz)) = hp;
            }
        }
        wg_barrier();   // (e) h ready

        // ---- GEMM2 swapped + fused mask*column-sum
        {
            f32x4 acc2[2];
            #pragma unroll
            for (int ct = 0; ct < 2; ++ct)
                acc2[ct] = (f32x4){bias2[ct][0], bias2[ct][1], bias2[ct][2], bias2[ct][3]};
            #pragma unroll
            for (int ks = 0; ks < 6; ++ks) {
                bf16x8 a = *(const bf16x8*)((char*)h_s + row * 384 + ((ks * 64 + lg * 16) ^ swz));
                #pragma unroll
                for (int ct = 0; ct < 2; ++ct)
                    acc2[ct] = __builtin_amdgcn_mfma_f32_16x16x32_bf16(bw2[ct][ks], a, acc2[ct], 0, 0, 0);
            }
            float m = msk_s[bi][(cc & 3) * 16 + ln];
            #pragma unroll
            for (int ct = 0; ct < 2; ++ct)
                #pragma unroll
                for (int reg = 0; reg < 4; ++reg)
                    csum[ct][reg] = fmaf(fmaxf(acc2[ct][reg], 0.f), m, csum[ct][reg]);
        }

        // ---- end of b: row-butterfly reduce, l2norm, store
        if ((cc & 3) == 3) {
            #pragma unroll
            for (int s = 1; s < 16; s <<= 1)
                #pragma unroll
                for (int ct = 0; ct < 2; ++ct)
                    #pragma unroll
                    for (int reg = 0; reg < 4; ++reg)
                        csum[ct][reg] += __shfl_xor(csum[ct][reg], s, 64);
            if (ln == 0) {
                #pragma unroll
                for (int ct = 0; ct < 2; ++ct)
                    #pragma unroll
                    for (int reg = 0; reg < 4; ++reg)
                        redv[w * 32 + ct * 16 + lg * 4 + reg] = csum[ct][reg];
            }
            wg_barrier();
            float v = 0.f;
            if (tid < 128) {
                v = redv[tid] / ncol_s[bi];
                float s2 = v * v;
                #pragma unroll
                for (int sh = 1; sh < 64; sh <<= 1) s2 += __shfl_xor(s2, sh, 64);
                if (l == 0) redq[w] = s2;
            }
            wg_barrier();
            if (tid < 128) {
                float inv = rsqrtf(fmaxf(redq[0] + redq[1], 1e-12f));
                te_out[(size_t)(bb0 + bi) * D_ + tid] = v * inv;
            }
            #pragma unroll
            for (int ct = 0; ct < 2; ++ct)
                #pragma unroll
                for (int reg = 0; reg < 4; ++reg)
                    csum[ct][reg] = 0.f;
        }
    };

    for (int p = 0; p < 8; ++p) {
        body(p * 2,     pf0, (char*)flat_s[0]);
        body(p * 2 + 1, pf1, (char*)flat_s[1]);
    }
}

// ---------------------------------------------------------------------------
// LSTM (round-5 version, reverted): 256 blocks x 512 threads, 16 rows/block,
// depth-1 x prefetch, raw barriers, weights pinned resident.
// ---------------------------------------------------------------------------
__global__ __launch_bounds__(512) __attribute__((amdgpu_waves_per_eu(1, 2)))
void lstm_kernel(
    const float* __restrict__ q, const int* __restrict__ lengths,
    const short* __restrict__ WTl, const float* __restrict__ bl,
    float* __restrict__ qe_out)
{
    const int tid = threadIdx.x;
    const int b0  = blockIdx.x * 16;
    const int w   = tid >> 6;
    const int l   = tid & 63;
    const int lg  = l >> 4;
    const int ln  = l & 15;       // batch row within block
    const int d0  = w * 16 + lg * 4;

    __shared__ __align__(16) short xh[2][16 * 256];  // 2 x 8 KB, swizzled
    __shared__ float red8[8][16];

    bf16x8 wf[4][8];
    #pragma unroll
    for (int g = 0; g < 4; ++g)
        #pragma unroll
        for (int ks = 0; ks < 8; ++ks)
            wf[g][ks] = *(const bf16x8*)&WTl[(w * 64 + g * 16 + ln) * 256 + ks * 32 + lg * 8];
    float bias[4][4];
    #pragma unroll
    for (int g = 0; g < 4; ++g)
        #pragma unroll
        for (int reg = 0; reg < 4; ++reg)
            bias[g][reg] = bl[g * 128 + d0 + reg];
    #pragma unroll
    for (int g = 0; g < 4; ++g) {
        #pragma unroll
        for (int ks = 0; ks < 8; ++ks) KEEP(wf[g][ks]);
        #pragma unroll
        for (int reg = 0; reg < 4; ++reg) KEEP(bias[g][reg]);
    }

    float creg[4] = {0.f, 0.f, 0.f, 0.f};
    float hreg[4] = {0.f, 0.f, 0.f, 0.f};
    const int len = lengths[b0 + ln];
    const int sr = tid >> 5, sc = tid & 31;

    // prefetch x_0
    float4 qv = *(const float4*)&q[((size_t)(b0 + sr) * LQ_ + 0) * D_ + sc * 4];

    for (int t = 0; t < LQ_; ++t) {
        char* buf = (char*)xh[t & 1];
        // stage x_t from prefetched regs
        uint2 px; px.x = cvt_pk_bf16(qv.x, qv.y); px.y = cvt_pk_bf16(qv.z, qv.w);
        *(uint2*)(buf + sr * 512 + ((sc * 8) ^ ((sr & 7) << 4))) = px;
        // write h(t-1)
        uint2 ph; ph.x = cvt_pk_bf16(hreg[0], hreg[1]); ph.y = cvt_pk_bf16(hreg[2], hreg[3]);
        *(uint2*)(buf + ln * 512 + ((256 + d0 * 2) ^ ((ln & 7) << 4))) = ph;
        // prefetch x_{t+1}: stays in flight across the raw barrier + MFMA
        if (t + 1 < LQ_)
            qv = *(const float4*)&q[((size_t)(b0 + sr) * LQ_ + (t + 1)) * D_ + sc * 4];
        wg_barrier();

        f32x4 acc[4];
        #pragma unroll
        for (int g = 0; g < 4; ++g)
            acc[g] = (f32x4){bias[g][0], bias[g][1], bias[g][2], bias[g][3]};
        #pragma unroll
        for (int ks = 0; ks < 8; ++ks) {
            bf16x8 xf = *(const bf16x8*)(buf + ln * 512 + ((ks * 64 + lg * 16) ^ ((ln & 7) << 4)));
            #pragma unroll
            for (int g = 0; g < 4; ++g)
                acc[g] = __builtin_amdgcn_mfma_f32_16x16x32_bf16(wf[g][ks], xf, acc[g], 0, 0, 0);
        }

        bool live = (t < len);
        #pragma unroll
        for (int reg = 0; reg < 4; ++reg) {
            float iv = sigm(acc[0][reg]);
            float fv = sigm(acc[1][reg]);
            float gv = fmaxf(acc[2][reg], 0.f);
            float ov = sigm(acc[3][reg]);
            float cn = fmaf(fv, creg[reg], iv * gv);
            float hn = ov * fmaxf(cn, 0.f);
            if (live) { creg[reg] = cn; hreg[reg] = hn; }
        }
    }

    // l2norm per batch row
    float sq = 0.f;
    #pragma unroll
    for (int reg = 0; reg < 4; ++reg) sq = fmaf(hreg[reg], hreg[reg], sq);
    sq += __shfl_xor(sq, 16, 64);
    sq += __shfl_xor(sq, 32, 64);
    if (l < 16) red8[w][ln] = sq;
    wg_barrier();
    float tot = 0.f;
    #pragma unroll
    for (int ww = 0; ww < 8; ++ww) tot += red8[ww][ln];
    float inv = rsqrtf(fmaxf(tot, 1e-12f));
    float4 o;
    o.x = hreg[0] * inv; o.y = hreg[1] * inv; o.z = hreg[2] * inv; o.w = hreg[3] * inv;
    *(float4*)&qe_out[(size_t)(b0 + ln) * D_ + d0] = o;
}

// ---------------------------------------------------------------------------
// Loss: 64 blocks x 64 threads, 1 sample per thread.
// ---------------------------------------------------------------------------
__global__ __launch_bounds__(64) void loss_kernel(
    const float* __restrict__ te, const float* __restrict__ qe,
    const float* __restrict__ labels, float* __restrict__ partial)
{
    const int tid = threadIdx.x;
    const int b   = blockIdx.x * 64 + tid;
    float dsum = 0.f;
    #pragma unroll 8
    for (int k4 = 0; k4 < 32; ++k4) {
        float4 a = *(const float4*)&qe[(size_t)b * D_ + k4 * 4];
        float4 c = *(const float4*)&te[(size_t)b * D_ + k4 * 4];
        float dx = a.x - c.x, dy = a.y - c.y, dz = a.z - c.z, dw = a.w - c.w;
        dsum += dx * dx + dy * dy + dz * dz + dw * dw;
    }
    float lab = labels[b];
    float ds  = sqrtf(dsum);
    float ml  = fmaxf(0.f, 1.f - ds);
    float loss = lab * dsum + (1.f - lab) * ml * ml;
    #pragma unroll
    for (int s = 32; s > 0; s >>= 1) loss += __shfl_xor(loss, s, 64);
    if (tid == 0) partial[blockIdx.x] = loss;
}

__global__ void final_kernel(const float* __restrict__ partial, float* __restrict__ out)
{
    const int tid = threadIdx.x;   // 64 threads
    float v = partial[tid];
    #pragma unroll
    for (int s = 32; s > 0; s >>= 1) v += __shfl_xor(v, s, 64);
    if (tid == 0) out[0] = 0.5f * v / (float)B_;
}

// ---------------------------------------------------------------------------
extern "C" void kernel_launch(void* const* d_in, const int* in_sizes, int n_in,
                              void* d_out, int out_size, void* d_ws, size_t ws_size,
                              hipStream_t stream)
{
    const float* q      = (const float*)d_in[0];
    const int*   qlen   = (const int*)d_in[1];
    const float* header = (const float*)d_in[2];
    const float* tword  = (const float*)d_in[3];
    const int*   ncols  = (const int*)d_in[4];
    const float* masks  = (const float*)d_in[5];
    const float* labels = (const float*)d_in[6];
    const float* W1     = (const float*)d_in[7];
    const float* b1     = (const float*)d_in[8];
    const float* W2     = (const float*)d_in[9];
    const float* b2     = (const float*)d_in[10];
    const float* Wx     = (const float*)d_in[11];
    const float* Wh     = (const float*)d_in[12];
    const float* bl     = (const float*)d_in[13];
    float* out = (float*)d_out;

    float* te      = (float*)d_ws;
    float* qe      = te + (size_t)B_ * D_;
    float* partial = qe + (size_t)B_ * D_;
    short* W1T     = (short*)(partial + 64);          // 192*256
    short* W2T     = W1T + 192 * 256;                 // 128*192
    short* WTl     = W2T + 128 * 192;                 // 512*256

    prep_kernel<<<512, 256, 0, stream>>>(W1, W2, Wx, Wh, W1T, W2T, WTl);
    table_kernel<<<B_ / 4, 256, 0, stream>>>(header, tword, masks, ncols, W1T, b1, W2T, b2, te);
    lstm_kernel<<<B_ / 16, 512, 0, stream>>>(q, qlen, WTl, bl, qe);
    loss_kernel<<<B_ / 64, 64, 0, stream>>>(te, qe, labels, partial);
    final_kernel<<<1, 64, 0, stream>>>(partial, out);
}